// Round 7
// baseline (410.612 us; speedup 1.0000x reference)
//
#include <hip/hip_runtime.h>

#define HALF 128
#define NMAT 16384   // 128*128
#define NTOK 131072  // 32*4096

typedef float f4 __attribute__((ext_vector_type(4)));

// ---------------------------------------------------------------------------
// K1: fused Cayley -> QT.  Q^T = N^{-1}(2I - N) = 2 N^{-1} - I,  N = I + A/2.
// BLOCKED Gauss-Jordan (panel b=16), 8 block-steps, 4x8 register tiles.
// ROUND-4 VERIFIED FORM.  A/A RE-BENCH: round 4 measured 271.7 us total with
// this exact codegen; round 6 measured 405.2 (cayley_qt 199 us/dispatch) with
// zero source change -- re-measuring to classify the anomaly before editing.
// ---------------------------------------------------------------------------
__global__ __launch_bounds__(512) void cayley_qt(const float* __restrict__ prim,
                                                 float* __restrict__ QT) {
    __shared__ __align__(16) float Xs[128 * 129];   // padded input stage
    __shared__ __align__(16) float Cp[2][128][20];  // C panel, [r][m] (dbuf)
    __shared__ __align__(16) float Rp[16][132];     // R panel, [j][c]
    __shared__ __align__(16) float Dcol[16][20];    // Dcol[j][m] = Dinv[m][j]
    __shared__ __align__(16) float RB[16][132];     // coeff: RB[m][c]

    const int b = blockIdx.x;
    const float* __restrict__ X = prim + b * NMAT;
    const int t  = threadIdx.x;
    const int rg = t >> 4;           // row group: rows 4rg..4rg+3
    const int cg = t & 15;           // col group: cols 8cg..8cg+7

    for (int idx4 = t; idx4 < 4096; idx4 += 512) {
        int gi = idx4 << 2;
        float4 v = *(const float4*)(X + gi);
        int r = gi >> 7, cc = gi & 127;
        float* xp = &Xs[r * 129 + cc];
        xp[0] = v.x; xp[1] = v.y; xp[2] = v.z; xp[3] = v.w;
    }
    __syncthreads();

    // reg[i][jj] = N[4rg+i][8cg+jj];  A = tril(X) - tril(X)^T
    float reg[4][8];
    #pragma unroll
    for (int i = 0; i < 4; ++i) {
        const int r = (rg << 2) + i;
        #pragma unroll
        for (int jj = 0; jj < 8; ++jj) {
            const int c = (cg << 3) + jj;
            int mx = r > c ? r : c;
            int mn = r ^ c ^ mx;
            float x = Xs[mx * 129 + mn];
            reg[i][jj] = (r == c) ? 1.0f : (r > c ? 0.5f * x : -0.5f * x);
        }
    }

    #pragma unroll
    for (int s = 0; s < 8; ++s) {
        const int  p    = s & 1;
        const int  k0   = s << 4;
        const bool pubC = (cg >> 1) == s;   // this tile's 8 cols inside K
        const bool pubR = (rg >> 2) == s;   // this tile's 4 rows inside K

        // ---- A. publish pre-step panels
        if (pubC) {
            const int mb = (cg & 1) << 3;   // m = (8cg+jj) - k0 = mb + jj
            #pragma unroll
            for (int i = 0; i < 4; ++i) {
                *(float4*)&Cp[p][(rg << 2) + i][mb] =
                    make_float4(reg[i][0], reg[i][1], reg[i][2], reg[i][3]);
                *(float4*)&Cp[p][(rg << 2) + i][mb + 4] =
                    make_float4(reg[i][4], reg[i][5], reg[i][6], reg[i][7]);
            }
        }
        if (pubR) {
            const int jb = (rg & 3) << 2;   // local row j = jb + i
            #pragma unroll
            for (int i = 0; i < 4; ++i) {
                *(float4*)&Rp[jb + i][cg << 3] =
                    make_float4(reg[i][0], reg[i][1], reg[i][2], reg[i][3]);
                *(float4*)&Rp[jb + i][(cg << 3) + 4] =
                    make_float4(reg[i][4], reg[i][5], reg[i][6], reg[i][7]);
            }
        }
        __syncthreads();

        // ---- C. wave 0: invert D (16x16) in registers, shuffle-based GJ
        if (t < 64) {
            const int cp = t & 15, q4 = t >> 4;
            float dd[4];
            #pragma unroll
            for (int i = 0; i < 4; ++i) dd[i] = Rp[q4 * 4 + i][k0 + cp];
            #pragma unroll
            for (int k = 0; k < 16; ++k) {
                float cv[4];
                #pragma unroll
                for (int i = 0; i < 4; ++i) cv[i] = __shfl(dd[i], (q4 << 4) | k);
                float rv   = __shfl(dd[k & 3], ((k >> 2) << 4) | cp);
                float dkk  = __shfl(rv, k);
                float dinv = 1.0f / dkk;
                float sv   = rv * dinv;
                bool  own  = (cp == k);
                float rf   = own ? dinv : sv;
                #pragma unroll
                for (int i = 0; i < 4; ++i)
                    dd[i] = own ? (-dd[i] * dinv) : fmaf(-cv[i], sv, dd[i]);
                dd[k & 3] = (q4 == (k >> 2)) ? rf : dd[k & 3];
            }
            #pragma unroll
            for (int i = 0; i < 4; ++i) Dcol[cp][q4 * 4 + i] = dd[i];
        }
        __syncthreads();

        // ---- E. build RB[m][c] cooperatively (512 thr x 4 entries)
        {
            const int m  = t >> 5;
            const int qd = t & 31;
            const int cb = qd << 2;          // cols cb..cb+3
            float4 acc;
            if ((qd >> 2) == s) {
                // panel cols: RB[m][k0+mp] = Dinv[m][mp] = Dcol[mp][m] (copy)
                acc.x = Dcol[cb + 0 - k0][m];
                acc.y = Dcol[cb + 1 - k0][m];
                acc.z = Dcol[cb + 2 - k0][m];
                acc.w = Dcol[cb + 3 - k0][m];
            } else {
                acc = make_float4(0.f, 0.f, 0.f, 0.f);
                #pragma unroll
                for (int j = 0; j < 16; ++j) {          // j ascending (as old)
                    float  dj = Dcol[j][m];
                    float4 r4 = *(const float4*)&Rp[j][cb];
                    acc.x = fmaf(dj, r4.x, acc.x);
                    acc.y = fmaf(dj, r4.y, acc.y);
                    acc.z = fmaf(dj, r4.z, acc.z);
                    acc.w = fmaf(dj, r4.w, acc.w);
                }
            }
            *(float4*)&RB[m][cb] = acc;
        }
        __syncthreads();

        // ---- G. rank-16 update on the 4x8 tile (C in regs, RB streamed)
        float crs[4][16];
        #pragma unroll
        for (int i = 0; i < 4; ++i)
            #pragma unroll
            for (int mq = 0; mq < 4; ++mq) {
                float4 v = *(const float4*)&Cp[p][(rg << 2) + i][mq << 2];
                crs[i][4 * mq + 0] = v.x; crs[i][4 * mq + 1] = v.y;
                crs[i][4 * mq + 2] = v.z; crs[i][4 * mq + 3] = v.w;
            }
        if (pubC) {
            #pragma unroll
            for (int i = 0; i < 4; ++i)
                #pragma unroll
                for (int jj = 0; jj < 8; ++jj) reg[i][jj] = 0.0f;
        }
        #pragma unroll
        for (int m = 0; m < 16; ++m) {       // m ascending (as old)
            float4 rb0 = *(const float4*)&RB[m][cg << 3];
            float4 rb1 = *(const float4*)&RB[m][(cg << 3) + 4];
            #pragma unroll
            for (int i = 0; i < 4; ++i) {
                float cm = crs[i][m];
                reg[i][0] = fmaf(-cm, rb0.x, reg[i][0]);
                reg[i][1] = fmaf(-cm, rb0.y, reg[i][1]);
                reg[i][2] = fmaf(-cm, rb0.z, reg[i][2]);
                reg[i][3] = fmaf(-cm, rb0.w, reg[i][3]);
                reg[i][4] = fmaf(-cm, rb1.x, reg[i][4]);
                reg[i][5] = fmaf(-cm, rb1.y, reg[i][5]);
                reg[i][6] = fmaf(-cm, rb1.z, reg[i][6]);
                reg[i][7] = fmaf(-cm, rb1.w, reg[i][7]);
            }
        }
        if (pubR) {                          // rows K: W[K,:] = RB
            const int jb = (rg & 3) << 2;
            #pragma unroll
            for (int i = 0; i < 4; ++i) {
                float4 a = *(const float4*)&RB[jb + i][cg << 3];
                float4 b2 = *(const float4*)&RB[jb + i][(cg << 3) + 4];
                reg[i][0] = a.x;  reg[i][1] = a.y;  reg[i][2] = a.z;  reg[i][3] = a.w;
                reg[i][4] = b2.x; reg[i][5] = b2.y; reg[i][6] = b2.z; reg[i][7] = b2.w;
            }
        }
    }

    float* __restrict__ out = QT + b * NMAT;
    #pragma unroll
    for (int i = 0; i < 4; ++i) {
        const int r  = (rg << 2) + i;
        const int c0 = cg << 3;
        float4 o0, o1;
        o0.x = 2.0f * reg[i][0] - (r == c0 + 0 ? 1.0f : 0.0f);
        o0.y = 2.0f * reg[i][1] - (r == c0 + 1 ? 1.0f : 0.0f);
        o0.z = 2.0f * reg[i][2] - (r == c0 + 2 ? 1.0f : 0.0f);
        o0.w = 2.0f * reg[i][3] - (r == c0 + 3 ? 1.0f : 0.0f);
        o1.x = 2.0f * reg[i][4] - (r == c0 + 4 ? 1.0f : 0.0f);
        o1.y = 2.0f * reg[i][5] - (r == c0 + 5 ? 1.0f : 0.0f);
        o1.z = 2.0f * reg[i][6] - (r == c0 + 6 ? 1.0f : 0.0f);
        o1.w = 2.0f * reg[i][7] - (r == c0 + 7 ? 1.0f : 0.0f);
        *(float4*)&out[r * HALF + c0]     = o0;
        *(float4*)&out[r * HALF + c0 + 4] = o1;
    }
}

// ---------------------------------------------------------------------------
// K2a: rows [0,256) from identity, steps d=0..6.  ROUND-2 VERIFIED FORM.
// ---------------------------------------------------------------------------
__global__ __launch_bounds__(256) void path_base(const float* __restrict__ QT,
                                                 const float* __restrict__ ident,
                                                 float* __restrict__ P) {
    __shared__ __align__(16) float vs[2][4][HALF];
    const int t    = threadIdx.x;
    const int rg   = t >> 6;                 // row in block (0..3), one wave each
    const int jj   = (t & 63) << 1;          // 2-col chunk
    const int v    = (blockIdx.x << 2) + rg;
    const int vmax = (blockIdx.x << 2) + 3;

    float2 cv = *(const float2*)&ident[jj];
    *(float2*)&vs[0][rg][jj] = cv;
    __syncthreads();

    int cur = 0;
    for (int d = 0; d < 8; ++d) {
        if ((vmax >> (d + 1)) == 0) break;           // block-uniform
        const bool valid = (v >> (d + 1)) > 0;
        const float* __restrict__ Qm = QT + (((v >> d) & 1) ? NMAT : 0);
        float2 acc = make_float2(0.f, 0.f);
        #pragma unroll 4
        for (int cc = 0; cc < 128; cc += 4) {
            float4 v4 = *(const float4*)&vs[cur][rg][cc];
            float2 q0 = *(const float2*)&Qm[(cc+0)*HALF + jj];
            float2 q1 = *(const float2*)&Qm[(cc+1)*HALF + jj];
            float2 q2 = *(const float2*)&Qm[(cc+2)*HALF + jj];
            float2 q3 = *(const float2*)&Qm[(cc+3)*HALF + jj];
            acc.x = fmaf(v4.x,q0.x, fmaf(v4.y,q1.x, fmaf(v4.z,q2.x, fmaf(v4.w,q3.x, acc.x))));
            acc.y = fmaf(v4.x,q0.y, fmaf(v4.y,q1.y, fmaf(v4.z,q2.y, fmaf(v4.w,q3.y, acc.y))));
        }
        if (valid) cv = acc;
        *(float2*)&vs[cur ^ 1][rg][jj] = cv;
        __syncthreads();
        cur ^= 1;
    }
    *(float2*)&P[v * HALF + jj] = cv;
}

// ---------------------------------------------------------------------------
// K2b: rows [256,4096), k-grouped, column-parallel, 256 threads (4 waves/
// block -- TLP sweet spot per round-5 evidence).  ROUND-4 VERIFIED FORM.
// ---------------------------------------------------------------------------
__global__ __launch_bounds__(256) void path_upper(const float* __restrict__ QT,
                                                  float* __restrict__ P) {
    __shared__ __align__(16) float vs[2][8][HALF];   // double-buffered row vals
    const int t  = threadIdx.x;
    const int j  = t & 127;                // owned output column
    const int h  = t >> 7;                 // row half: rows h*4 .. h*4+3
    const int k  = 2 + (blockIdx.x >> 4);  // 30 k-values x 16 blocks = 480
    const int r0 = (blockIdx.x & 15) << 3; // 8 residues per block

    float acc[4];
    #pragma unroll
    for (int rr = 0; rr < 4; ++rr)
        acc[rr] = P[(128 + r0 + h * 4 + rr) * HALF + j];

    int p = 0;
    for (int d = 7; d < 13; ++d) {
        if ((k >> (d - 6)) == 0) break;              // block-uniform
        const float* __restrict__ Qm = QT + (((k >> (d - 7)) & 1) ? NMAT : 0);
        #pragma unroll
        for (int rr = 0; rr < 4; ++rr) vs[p][h * 4 + rr][j] = acc[rr];
        __syncthreads();                             // other buffer still live

        float nacc[4] = {0.f, 0.f, 0.f, 0.f};
        #pragma unroll 4
        for (int cc = 0; cc < 128; cc += 4) {
            float q0 = Qm[(cc + 0) * HALF + j];      // coalesced global dword
            float q1 = Qm[(cc + 1) * HALF + j];
            float q2 = Qm[(cc + 2) * HALF + j];
            float q3 = Qm[(cc + 3) * HALF + j];
            #pragma unroll
            for (int rr = 0; rr < 4; ++rr) {
                float4 v4 = *(const float4*)&vs[p][h * 4 + rr][cc];  // broadcast
                nacc[rr] = fmaf(v4.x, q0,
                           fmaf(v4.y, q1,
                           fmaf(v4.z, q2,
                           fmaf(v4.w, q3, nacc[rr]))));
            }
        }
        #pragma unroll
        for (int rr = 0; rr < 4; ++rr) acc[rr] = nacc[rr];
        p ^= 1;                                      // next step: other buffer
    }

    #pragma unroll
    for (int rr = 0; rr < 4; ++rr)
        P[((k << 7) | (r0 + h * 4 + rr)) * HALF + j] = acc[rr];
}

// ---------------------------------------------------------------------------
// K3: emit [B,S,256] = content ++ pos.  ROUND-2 VERIFIED FORM (NT stores;
// at the ~21 us HBM write floor).
// ---------------------------------------------------------------------------
__global__ __launch_bounds__(256) void emit_out(const int* __restrict__ tt,
                                                const int* __restrict__ tv,
                                                const int* __restrict__ np,
                                                const float* __restrict__ P,
                                                const float* __restrict__ emb,
                                                float* __restrict__ out) {
    const int i  = (blockIdx.x << 2) + (threadIdx.x >> 6);
    const int jj = (threadIdx.x & 63) << 2;
    const int ty = tt[i];
    const int v  = tv[i];
    f4 val;
    if (jj < 128) {
        if (ty == 0)      val = *(const f4*)&emb[jj];
        else if (ty == 1) val = *(const f4*)&emb[(v + 1) * HALF + jj];
        else if (ty == 2) val = *(const f4*)&emb[(v + 5) * HALF + jj];
        else if (ty == 4) {
            int vc = v < 0 ? 0 : (v > 4095 ? 4095 : v);
            val = *(const f4*)&P[vc * HALF + jj];
        } else if (v == -1) val = *(const f4*)&emb[10 * HALF + jj];
        else { f4 z = {0.f, 0.f, 0.f, 0.f}; val = z; }
    } else {
        const int p = np[i];
        val = *(const f4*)&P[p * HALF + (jj - 128)];
    }
    __builtin_nontemporal_store(val, (f4*)&out[i * 256 + jj]);
}

extern "C" void kernel_launch(void* const* d_in, const int* in_sizes, int n_in,
                              void* d_out, int out_size, void* d_ws, size_t ws_size,
                              hipStream_t stream) {
    const int*   token_types = (const int*)  d_in[0];
    const int*   token_vals  = (const int*)  d_in[1];
    const int*   node_pos    = (const int*)  d_in[2];
    const float* prim        = (const float*)d_in[3];
    const float* ident       = (const float*)d_in[4];
    const float* emb         = (const float*)d_in[5];
    float* out = (float*)d_out;

    // workspace: QT[2][128][128] | (gap) | P[4096][128]
    float* QT = (float*)d_ws;
    float* P  = (float*)((char*)d_ws + 262144);

    cayley_qt  <<<2,   512, 0, stream>>>(prim, QT);
    path_base  <<<64,  256, 0, stream>>>(QT, ident, P);     // rows [0,256)
    path_upper <<<480, 256, 0, stream>>>(QT, P);            // rows [256,4096)
    emit_out   <<<NTOK / 4, 256, 0, stream>>>(token_types, token_vals, node_pos,
                                              P, emb, out);
}

// Round 8
// 304.744 us; speedup vs baseline: 1.3474x; 1.3474x over previous
//
#include <hip/hip_runtime.h>

#define HALF 128
#define NMAT 16384   // 128*128
#define NTOK 131072  // 32*4096

typedef float f4 __attribute__((ext_vector_type(4)));

// N[r][c] for N = I + A/2, A = tril(X) - tril(X)^T  (identical math/order to
// the verified monolithic K1's reg-init).
__device__ __forceinline__ float nval(const float* __restrict__ X, int r, int c) {
    int mx = r > c ? r : c;
    int mn = r ^ c ^ mx;
    float x = X[mx * HALF + mn];
    return (r == c) ? 1.0f : (r > c ? 0.5f * x : -0.5f * x);
}

// ---------------------------------------------------------------------------
// K1 (round-8): blocked Gauss-Jordan split into per-step kernel pairs so the
// update runs on 16 CUs instead of 2.  Round-7 evidence: the monolithic
// 2-block kernel is ~93% stalled for 202 us in the current environment
// (latency chain on 2 CUs); graph launches are ~free (rounds 1-5: zero gap).
// W lives IN-PLACE in the QT buffer; step 0 reads N from prim (no init
// kernel); step 7 writes QT = 2*W - I.  All per-element fma sequences are
// verbatim from the verified kernel -> bit-identical output.
// ---------------------------------------------------------------------------

// (a) panel kernel: 2 blocks (one per matrix) x 256 threads.
//     GJ-invert D = W[K,K] (wave 0, shuffle -- verbatim), then RB = Dinv*R
//     with Dinv copied into panel cols.  RBws: [2][16][128].
template<int S, bool FIRST>
__global__ __launch_bounds__(256) void k1_panel(const float* __restrict__ prim,
                                                const float* __restrict__ W,
                                                float* __restrict__ RBws) {
    __shared__ __align__(16) float Rs[16][132];   // R = pre-step W[K,:]
    __shared__ float Dc[16][17];                  // Dc[a][b] = Dinv[b][a]
    const int b  = blockIdx.x;
    const int t  = threadIdx.x;
    const int k0 = S << 4;
    const float* __restrict__ X  = prim + b * NMAT;
    const float* __restrict__ Wb = W + b * NMAT;

    {   // stage R: row j = t>>4, cols 8*(t&15)..+8
        const int j  = t >> 4;
        const int c0 = (t & 15) << 3;
        if (FIRST) {
            #pragma unroll
            for (int u = 0; u < 8; ++u) Rs[j][c0 + u] = nval(X, k0 + j, c0 + u);
        } else {
            float4 a  = *(const float4*)&Wb[(k0 + j) * HALF + c0];
            float4 b2 = *(const float4*)&Wb[(k0 + j) * HALF + c0 + 4];
            *(float4*)&Rs[j][c0]     = a;
            *(float4*)&Rs[j][c0 + 4] = b2;
        }
    }
    __syncthreads();

    if (t < 64) {   // wave 0: shuffle-GJ (verbatim from verified kernel)
        const int cp = t & 15, q4 = t >> 4;
        float dd[4];
        #pragma unroll
        for (int i = 0; i < 4; ++i) dd[i] = Rs[q4 * 4 + i][k0 + cp];
        #pragma unroll
        for (int k = 0; k < 16; ++k) {
            float cv[4];
            #pragma unroll
            for (int i = 0; i < 4; ++i) cv[i] = __shfl(dd[i], (q4 << 4) | k);
            float rv   = __shfl(dd[k & 3], ((k >> 2) << 4) | cp);
            float dkk  = __shfl(rv, k);
            float dinv = 1.0f / dkk;
            float sv   = rv * dinv;
            bool  own  = (cp == k);
            float rf   = own ? dinv : sv;
            #pragma unroll
            for (int i = 0; i < 4; ++i)
                dd[i] = own ? (-dd[i] * dinv) : fmaf(-cv[i], sv, dd[i]);
            dd[k & 3] = (q4 == (k >> 2)) ? rf : dd[k & 3];
        }
        #pragma unroll
        for (int i = 0; i < 4; ++i) Dc[cp][q4 * 4 + i] = dd[i];
    }
    __syncthreads();

    {   // RB[m][c]: m = t>>4, cols 8*(t&15)..+8; j ascending (as verified E)
        const int m  = t >> 4;
        const int c0 = (t & 15) << 3;
        float* __restrict__ RBb = RBws + b * (16 * HALF);
        if (c0 == k0 || c0 == k0 + 8) {
            #pragma unroll
            for (int u = 0; u < 8; ++u) RBb[m * HALF + c0 + u] = Dc[c0 + u - k0][m];
        } else {
            float acc[8] = {0.f,0.f,0.f,0.f,0.f,0.f,0.f,0.f};
            #pragma unroll
            for (int j = 0; j < 16; ++j) {
                float dj = Dc[j][m];
                #pragma unroll
                for (int u = 0; u < 8; ++u)
                    acc[u] = fmaf(dj, Rs[j][c0 + u], acc[u]);
            }
            *(float4*)&RBb[m * HALF + c0]     = make_float4(acc[0], acc[1], acc[2], acc[3]);
            *(float4*)&RBb[m * HALF + c0 + 4] = make_float4(acc[4], acc[5], acc[6], acc[7]);
        }
    }
}

// (b) update kernel: 16 blocks (2 matrices x 8 row-groups) x 256 threads.
//     Block owns 16 rows.  C-slice staged in LDS pre-barrier (in-place safe:
//     a block reads only its OWN rows; RB comes from the ws snapshot).
template<int S, bool FIRST, bool LAST>
__global__ __launch_bounds__(256) void k1_update(const float* __restrict__ prim,
                                                 float* __restrict__ W,
                                                 const float* __restrict__ RBws) {
    __shared__ __align__(16) float RBs[16][132];
    __shared__ float Cs[16][17];
    const int blk = blockIdx.x;
    const int b   = blk >> 3;
    const int rg  = blk & 7;
    const int r0  = rg << 4;
    const int t   = threadIdx.x;
    const int k0  = S << 4;
    const float* __restrict__ X   = prim + b * NMAT;
    float* __restrict__ Wb        = W + b * NMAT;
    const float* __restrict__ RBb = RBws + b * (16 * HALF);

    {   // stage RB (16x128)
        const int m  = t >> 4;
        const int c0 = (t & 15) << 3;
        *(float4*)&RBs[m][c0]     = *(const float4*)&RBb[m * HALF + c0];
        *(float4*)&RBs[m][c0 + 4] = *(const float4*)&RBb[m * HALF + c0 + 4];
    }
    {   // stage C-slice: rows r0..r0+16, cols k0..k0+16 (pre-step values)
        const int rr = t >> 4, m = t & 15;
        Cs[rr][m] = FIRST ? nval(X, r0 + rr, k0 + m)
                          : Wb[(r0 + rr) * HALF + k0 + m];
    }
    __syncthreads();

    const int rr = t >> 4;
    const int r  = r0 + rr;
    const int c0 = (t & 15) << 3;
    float w[8];

    if (rg == S) {                       // rows K: W[K,:] = RB
        #pragma unroll
        for (int u = 0; u < 8; ++u) w[u] = RBs[rr][c0 + u];
    } else {
        const bool pan = (c0 == k0) || (c0 == k0 + 8);
        if (pan) {
            #pragma unroll
            for (int u = 0; u < 8; ++u) w[u] = 0.0f;
        } else if (FIRST) {
            #pragma unroll
            for (int u = 0; u < 8; ++u) w[u] = nval(X, r, c0 + u);
        } else {
            float4 a  = *(const float4*)&Wb[r * HALF + c0];
            float4 b2 = *(const float4*)&Wb[r * HALF + c0 + 4];
            w[0]=a.x; w[1]=a.y; w[2]=a.z; w[3]=a.w;
            w[4]=b2.x; w[5]=b2.y; w[6]=b2.z; w[7]=b2.w;
        }
        #pragma unroll
        for (int m = 0; m < 16; ++m) {   // m ascending (as verified G)
            float cm = Cs[rr][m];
            #pragma unroll
            for (int u = 0; u < 8; ++u)
                w[u] = fmaf(-cm, RBs[m][c0 + u], w[u]);
        }
    }

    if (LAST) {
        #pragma unroll
        for (int u = 0; u < 8; ++u)
            w[u] = 2.0f * w[u] - ((r == c0 + u) ? 1.0f : 0.0f);
    }
    *(float4*)&Wb[r * HALF + c0]     = make_float4(w[0], w[1], w[2], w[3]);
    *(float4*)&Wb[r * HALF + c0 + 4] = make_float4(w[4], w[5], w[6], w[7]);
}

// ---------------------------------------------------------------------------
// K2a: rows [0,256) from identity, steps d=0..6.  ROUND-2 VERIFIED FORM.
// ---------------------------------------------------------------------------
__global__ __launch_bounds__(256) void path_base(const float* __restrict__ QT,
                                                 const float* __restrict__ ident,
                                                 float* __restrict__ P) {
    __shared__ __align__(16) float vs[2][4][HALF];
    const int t    = threadIdx.x;
    const int rg   = t >> 6;                 // row in block (0..3), one wave each
    const int jj   = (t & 63) << 1;          // 2-col chunk
    const int v    = (blockIdx.x << 2) + rg;
    const int vmax = (blockIdx.x << 2) + 3;

    float2 cv = *(const float2*)&ident[jj];
    *(float2*)&vs[0][rg][jj] = cv;
    __syncthreads();

    int cur = 0;
    for (int d = 0; d < 8; ++d) {
        if ((vmax >> (d + 1)) == 0) break;           // block-uniform
        const bool valid = (v >> (d + 1)) > 0;
        const float* __restrict__ Qm = QT + (((v >> d) & 1) ? NMAT : 0);
        float2 acc = make_float2(0.f, 0.f);
        #pragma unroll 4
        for (int cc = 0; cc < 128; cc += 4) {
            float4 v4 = *(const float4*)&vs[cur][rg][cc];
            float2 q0 = *(const float2*)&Qm[(cc+0)*HALF + jj];
            float2 q1 = *(const float2*)&Qm[(cc+1)*HALF + jj];
            float2 q2 = *(const float2*)&Qm[(cc+2)*HALF + jj];
            float2 q3 = *(const float2*)&Qm[(cc+3)*HALF + jj];
            acc.x = fmaf(v4.x,q0.x, fmaf(v4.y,q1.x, fmaf(v4.z,q2.x, fmaf(v4.w,q3.x, acc.x))));
            acc.y = fmaf(v4.x,q0.y, fmaf(v4.y,q1.y, fmaf(v4.z,q2.y, fmaf(v4.w,q3.y, acc.y))));
        }
        if (valid) cv = acc;
        *(float2*)&vs[cur ^ 1][rg][jj] = cv;
        __syncthreads();
        cur ^= 1;
    }
    *(float2*)&P[v * HALF + jj] = cv;
}

// ---------------------------------------------------------------------------
// K2b: rows [256,4096), k-grouped, column-parallel, 256 threads.
// ROUND-4 VERIFIED FORM.
// ---------------------------------------------------------------------------
__global__ __launch_bounds__(256) void path_upper(const float* __restrict__ QT,
                                                  float* __restrict__ P) {
    __shared__ __align__(16) float vs[2][8][HALF];   // double-buffered row vals
    const int t  = threadIdx.x;
    const int j  = t & 127;                // owned output column
    const int h  = t >> 7;                 // row half: rows h*4 .. h*4+3
    const int k  = 2 + (blockIdx.x >> 4);  // 30 k-values x 16 blocks = 480
    const int r0 = (blockIdx.x & 15) << 3; // 8 residues per block

    float acc[4];
    #pragma unroll
    for (int rr = 0; rr < 4; ++rr)
        acc[rr] = P[(128 + r0 + h * 4 + rr) * HALF + j];

    int p = 0;
    for (int d = 7; d < 13; ++d) {
        if ((k >> (d - 6)) == 0) break;              // block-uniform
        const float* __restrict__ Qm = QT + (((k >> (d - 7)) & 1) ? NMAT : 0);
        #pragma unroll
        for (int rr = 0; rr < 4; ++rr) vs[p][h * 4 + rr][j] = acc[rr];
        __syncthreads();                             // other buffer still live

        float nacc[4] = {0.f, 0.f, 0.f, 0.f};
        #pragma unroll 4
        for (int cc = 0; cc < 128; cc += 4) {
            float q0 = Qm[(cc + 0) * HALF + j];      // coalesced global dword
            float q1 = Qm[(cc + 1) * HALF + j];
            float q2 = Qm[(cc + 2) * HALF + j];
            float q3 = Qm[(cc + 3) * HALF + j];
            #pragma unroll
            for (int rr = 0; rr < 4; ++rr) {
                float4 v4 = *(const float4*)&vs[p][h * 4 + rr][cc];  // broadcast
                nacc[rr] = fmaf(v4.x, q0,
                           fmaf(v4.y, q1,
                           fmaf(v4.z, q2,
                           fmaf(v4.w, q3, nacc[rr]))));
            }
        }
        #pragma unroll
        for (int rr = 0; rr < 4; ++rr) acc[rr] = nacc[rr];
        p ^= 1;                                      // next step: other buffer
    }

    #pragma unroll
    for (int rr = 0; rr < 4; ++rr)
        P[((k << 7) | (r0 + h * 4 + rr)) * HALF + j] = acc[rr];
}

// ---------------------------------------------------------------------------
// K3: emit [B,S,256] = content ++ pos.  ROUND-2 VERIFIED FORM (NT stores).
// ---------------------------------------------------------------------------
__global__ __launch_bounds__(256) void emit_out(const int* __restrict__ tt,
                                                const int* __restrict__ tv,
                                                const int* __restrict__ np,
                                                const float* __restrict__ P,
                                                const float* __restrict__ emb,
                                                float* __restrict__ out) {
    const int i  = (blockIdx.x << 2) + (threadIdx.x >> 6);
    const int jj = (threadIdx.x & 63) << 2;
    const int ty = tt[i];
    const int v  = tv[i];
    f4 val;
    if (jj < 128) {
        if (ty == 0)      val = *(const f4*)&emb[jj];
        else if (ty == 1) val = *(const f4*)&emb[(v + 1) * HALF + jj];
        else if (ty == 2) val = *(const f4*)&emb[(v + 5) * HALF + jj];
        else if (ty == 4) {
            int vc = v < 0 ? 0 : (v > 4095 ? 4095 : v);
            val = *(const f4*)&P[vc * HALF + jj];
        } else if (v == -1) val = *(const f4*)&emb[10 * HALF + jj];
        else { f4 z = {0.f, 0.f, 0.f, 0.f}; val = z; }
    } else {
        const int p = np[i];
        val = *(const f4*)&P[p * HALF + (jj - 128)];
    }
    __builtin_nontemporal_store(val, (f4*)&out[i * 256 + jj]);
}

extern "C" void kernel_launch(void* const* d_in, const int* in_sizes, int n_in,
                              void* d_out, int out_size, void* d_ws, size_t ws_size,
                              hipStream_t stream) {
    const int*   token_types = (const int*)  d_in[0];
    const int*   token_vals  = (const int*)  d_in[1];
    const int*   node_pos    = (const int*)  d_in[2];
    const float* prim        = (const float*)d_in[3];
    const float* ident       = (const float*)d_in[4];
    const float* emb         = (const float*)d_in[5];
    float* out = (float*)d_out;

    // workspace: QT[2][128][128] (doubles as GJ's W, in-place) | P[4096][128]
    //            | RB[2][16][128]
    float* QT = (float*)d_ws;
    float* P  = (float*)((char*)d_ws + 262144);
    float* RB = (float*)((char*)d_ws + 2359296);

    k1_panel <0, true        ><<<2,  256, 0, stream>>>(prim, QT, RB);
    k1_update<0, true,  false><<<16, 256, 0, stream>>>(prim, QT, RB);
    k1_panel <1, false       ><<<2,  256, 0, stream>>>(prim, QT, RB);
    k1_update<1, false, false><<<16, 256, 0, stream>>>(prim, QT, RB);
    k1_panel <2, false       ><<<2,  256, 0, stream>>>(prim, QT, RB);
    k1_update<2, false, false><<<16, 256, 0, stream>>>(prim, QT, RB);
    k1_panel <3, false       ><<<2,  256, 0, stream>>>(prim, QT, RB);
    k1_update<3, false, false><<<16, 256, 0, stream>>>(prim, QT, RB);
    k1_panel <4, false       ><<<2,  256, 0, stream>>>(prim, QT, RB);
    k1_update<4, false, false><<<16, 256, 0, stream>>>(prim, QT, RB);
    k1_panel <5, false       ><<<2,  256, 0, stream>>>(prim, QT, RB);
    k1_update<5, false, false><<<16, 256, 0, stream>>>(prim, QT, RB);
    k1_panel <6, false       ><<<2,  256, 0, stream>>>(prim, QT, RB);
    k1_update<6, false, false><<<16, 256, 0, stream>>>(prim, QT, RB);
    k1_panel <7, false       ><<<2,  256, 0, stream>>>(prim, QT, RB);
    k1_update<7, false, true ><<<16, 256, 0, stream>>>(prim, QT, RB);

    path_base  <<<64,  256, 0, stream>>>(QT, ident, P);     // rows [0,256)
    path_upper <<<480, 256, 0, stream>>>(QT, P);            // rows [256,4096)
    emit_out   <<<NTOK / 4, 256, 0, stream>>>(token_types, token_vals, node_pos,
                                              P, emb, out);
}

// Round 9
// 266.612 us; speedup vs baseline: 1.5401x; 1.1430x over previous
//
#include <hip/hip_runtime.h>

#define HALF 128
#define NMAT 16384   // 128*128
#define NTOK 131072  // 32*4096

typedef float f4 __attribute__((ext_vector_type(4)));

// N[r][c] for N = I + A/2, A = tril(X) - tril(X)^T  (identical math/order to
// the verified kernels' reg-init).
__device__ __forceinline__ float nval(const float* __restrict__ X, int r, int c) {
    int mx = r > c ? r : c;
    int mn = r ^ c ^ mx;
    float x = X[mx * HALF + mn];
    return (r == c) ? 1.0f : (r > c ? 0.5f * x : -0.5f * x);
}

// ---------------------------------------------------------------------------
// K1 (round-9): one kernel per GJ block-step (8 dispatches, was 16).
// Each of the 16 blocks (2 matrices x 8 row-groups) redundantly runs the
// 16x16 shuffle-GJ and builds RB = Dinv*R in its own LDS (~2K cycles --
// cheaper than a dispatch boundary, which costs ~5.5 us in this env per
// round-8 accounting).  In-launch races are eliminated by PING-PONG W
// buffers: step s reads Win, writes Wout (disjoint), so no block ever reads
// rows another block writes in the same launch.  Step 0 reads N from prim;
// step 7 writes QT = 2*W - I.  All per-element fma sequences verbatim from
// the round-8 passing kernel -> bit-identical output.
// ---------------------------------------------------------------------------
template<bool FIRST, bool LAST>
__global__ __launch_bounds__(256) void k1_step(const float* __restrict__ prim,
                                               const float* __restrict__ Win,
                                               float* __restrict__ Wout,
                                               int S) {
    __shared__ __align__(16) float Rs[16][132];   // R = pre-step W[K,:]
    __shared__ float Dc[16][17];                  // Dc[a][b] = Dinv[b][a]
    __shared__ __align__(16) float RBs[16][132];  // RB[m][c] (Dinv in panel cols)
    __shared__ float Cs[16][17];                  // own-rows C-slice

    const int blk = blockIdx.x;
    const int b   = blk >> 3;            // matrix
    const int rg  = blk & 7;             // row-group: rows r0..r0+15
    const int r0  = rg << 4;
    const int t   = threadIdx.x;
    const int k0  = S << 4;
    const float* __restrict__ X  = prim + b * NMAT;
    const float* __restrict__ Wi = Win  + b * NMAT;
    float*       __restrict__ Wo = Wout + b * NMAT;

    {   // stage R: row j = t>>4, cols 8*(t&15)..+8
        const int j  = t >> 4;
        const int c0 = (t & 15) << 3;
        if (FIRST) {
            #pragma unroll
            for (int u = 0; u < 8; ++u) Rs[j][c0 + u] = nval(X, k0 + j, c0 + u);
        } else {
            float4 a  = *(const float4*)&Wi[(k0 + j) * HALF + c0];
            float4 b2 = *(const float4*)&Wi[(k0 + j) * HALF + c0 + 4];
            *(float4*)&Rs[j][c0]     = a;
            *(float4*)&Rs[j][c0 + 4] = b2;
        }
    }
    {   // stage C-slice: rows r0..r0+16, cols k0..k0+16 (pre-step values)
        const int rr = t >> 4, m = t & 15;
        Cs[rr][m] = FIRST ? nval(X, r0 + rr, k0 + m)
                          : Wi[(r0 + rr) * HALF + k0 + m];
    }
    __syncthreads();

    if (t < 64) {   // wave 0: shuffle-GJ invert D (verbatim)
        const int cp = t & 15, q4 = t >> 4;
        float dd[4];
        #pragma unroll
        for (int i = 0; i < 4; ++i) dd[i] = Rs[q4 * 4 + i][k0 + cp];
        #pragma unroll
        for (int k = 0; k < 16; ++k) {
            float cv[4];
            #pragma unroll
            for (int i = 0; i < 4; ++i) cv[i] = __shfl(dd[i], (q4 << 4) | k);
            float rv   = __shfl(dd[k & 3], ((k >> 2) << 4) | cp);
            float dkk  = __shfl(rv, k);
            float dinv = 1.0f / dkk;
            float sv   = rv * dinv;
            bool  own  = (cp == k);
            float rf   = own ? dinv : sv;
            #pragma unroll
            for (int i = 0; i < 4; ++i)
                dd[i] = own ? (-dd[i] * dinv) : fmaf(-cv[i], sv, dd[i]);
            dd[k & 3] = (q4 == (k >> 2)) ? rf : dd[k & 3];
        }
        #pragma unroll
        for (int i = 0; i < 4; ++i) Dc[cp][q4 * 4 + i] = dd[i];
    }
    __syncthreads();

    {   // RB[m][c] in LDS: m = t>>4, cols 8*(t&15)..+8; j ascending (verbatim)
        const int m  = t >> 4;
        const int c0 = (t & 15) << 3;
        if (c0 == k0 || c0 == k0 + 8) {
            #pragma unroll
            for (int u = 0; u < 8; ++u) RBs[m][c0 + u] = Dc[c0 + u - k0][m];
        } else {
            float acc[8] = {0.f,0.f,0.f,0.f,0.f,0.f,0.f,0.f};
            #pragma unroll
            for (int j = 0; j < 16; ++j) {
                float dj = Dc[j][m];
                #pragma unroll
                for (int u = 0; u < 8; ++u)
                    acc[u] = fmaf(dj, Rs[j][c0 + u], acc[u]);
            }
            *(float4*)&RBs[m][c0]     = make_float4(acc[0], acc[1], acc[2], acc[3]);
            *(float4*)&RBs[m][c0 + 4] = make_float4(acc[4], acc[5], acc[6], acc[7]);
        }
    }
    __syncthreads();

    {   // update own 16 rows, write to Wout (disjoint -> race-free)
        const int rr = t >> 4;
        const int r  = r0 + rr;
        const int c0 = (t & 15) << 3;
        float w[8];

        if (rg == S) {                       // rows K: W[K,:] = RB
            #pragma unroll
            for (int u = 0; u < 8; ++u) w[u] = RBs[rr][c0 + u];
        } else {
            const bool pan = (c0 == k0) || (c0 == k0 + 8);
            if (pan) {
                #pragma unroll
                for (int u = 0; u < 8; ++u) w[u] = 0.0f;
            } else if (FIRST) {
                #pragma unroll
                for (int u = 0; u < 8; ++u) w[u] = nval(X, r, c0 + u);
            } else {
                float4 a  = *(const float4*)&Wi[r * HALF + c0];
                float4 b2 = *(const float4*)&Wi[r * HALF + c0 + 4];
                w[0]=a.x; w[1]=a.y; w[2]=a.z; w[3]=a.w;
                w[4]=b2.x; w[5]=b2.y; w[6]=b2.z; w[7]=b2.w;
            }
            #pragma unroll
            for (int m = 0; m < 16; ++m) {   // m ascending (verbatim)
                float cm = Cs[rr][m];
                #pragma unroll
                for (int u = 0; u < 8; ++u)
                    w[u] = fmaf(-cm, RBs[m][c0 + u], w[u]);
            }
        }

        if (LAST) {
            #pragma unroll
            for (int u = 0; u < 8; ++u)
                w[u] = 2.0f * w[u] - ((r == c0 + u) ? 1.0f : 0.0f);
        }
        *(float4*)&Wo[r * HALF + c0]     = make_float4(w[0], w[1], w[2], w[3]);
        *(float4*)&Wo[r * HALF + c0 + 4] = make_float4(w[4], w[5], w[6], w[7]);
    }
}

// ---------------------------------------------------------------------------
// K2a: rows [0,256) from identity, steps d=0..6.  ROUND-2 VERIFIED FORM.
// ---------------------------------------------------------------------------
__global__ __launch_bounds__(256) void path_base(const float* __restrict__ QT,
                                                 const float* __restrict__ ident,
                                                 float* __restrict__ P) {
    __shared__ __align__(16) float vs[2][4][HALF];
    const int t    = threadIdx.x;
    const int rg   = t >> 6;                 // row in block (0..3), one wave each
    const int jj   = (t & 63) << 1;          // 2-col chunk
    const int v    = (blockIdx.x << 2) + rg;
    const int vmax = (blockIdx.x << 2) + 3;

    float2 cv = *(const float2*)&ident[jj];
    *(float2*)&vs[0][rg][jj] = cv;
    __syncthreads();

    int cur = 0;
    for (int d = 0; d < 8; ++d) {
        if ((vmax >> (d + 1)) == 0) break;           // block-uniform
        const bool valid = (v >> (d + 1)) > 0;
        const float* __restrict__ Qm = QT + (((v >> d) & 1) ? NMAT : 0);
        float2 acc = make_float2(0.f, 0.f);
        #pragma unroll 4
        for (int cc = 0; cc < 128; cc += 4) {
            float4 v4 = *(const float4*)&vs[cur][rg][cc];
            float2 q0 = *(const float2*)&Qm[(cc+0)*HALF + jj];
            float2 q1 = *(const float2*)&Qm[(cc+1)*HALF + jj];
            float2 q2 = *(const float2*)&Qm[(cc+2)*HALF + jj];
            float2 q3 = *(const float2*)&Qm[(cc+3)*HALF + jj];
            acc.x = fmaf(v4.x,q0.x, fmaf(v4.y,q1.x, fmaf(v4.z,q2.x, fmaf(v4.w,q3.x, acc.x))));
            acc.y = fmaf(v4.x,q0.y, fmaf(v4.y,q1.y, fmaf(v4.z,q2.y, fmaf(v4.w,q3.y, acc.y))));
        }
        if (valid) cv = acc;
        *(float2*)&vs[cur ^ 1][rg][jj] = cv;
        __syncthreads();
        cur ^= 1;
    }
    *(float2*)&P[v * HALF + jj] = cv;
}

// ---------------------------------------------------------------------------
// K2b: rows [256,4096), k-grouped, column-parallel, 256 threads.
// ROUND-4 VERIFIED FORM.
// ---------------------------------------------------------------------------
__global__ __launch_bounds__(256) void path_upper(const float* __restrict__ QT,
                                                  float* __restrict__ P) {
    __shared__ __align__(16) float vs[2][8][HALF];   // double-buffered row vals
    const int t  = threadIdx.x;
    const int j  = t & 127;                // owned output column
    const int h  = t >> 7;                 // row half: rows h*4 .. h*4+3
    const int k  = 2 + (blockIdx.x >> 4);  // 30 k-values x 16 blocks = 480
    const int r0 = (blockIdx.x & 15) << 3; // 8 residues per block

    float acc[4];
    #pragma unroll
    for (int rr = 0; rr < 4; ++rr)
        acc[rr] = P[(128 + r0 + h * 4 + rr) * HALF + j];

    int p = 0;
    for (int d = 7; d < 13; ++d) {
        if ((k >> (d - 6)) == 0) break;              // block-uniform
        const float* __restrict__ Qm = QT + (((k >> (d - 7)) & 1) ? NMAT : 0);
        #pragma unroll
        for (int rr = 0; rr < 4; ++rr) vs[p][h * 4 + rr][j] = acc[rr];
        __syncthreads();                             // other buffer still live

        float nacc[4] = {0.f, 0.f, 0.f, 0.f};
        #pragma unroll 4
        for (int cc = 0; cc < 128; cc += 4) {
            float q0 = Qm[(cc + 0) * HALF + j];      // coalesced global dword
            float q1 = Qm[(cc + 1) * HALF + j];
            float q2 = Qm[(cc + 2) * HALF + j];
            float q3 = Qm[(cc + 3) * HALF + j];
            #pragma unroll
            for (int rr = 0; rr < 4; ++rr) {
                float4 v4 = *(const float4*)&vs[p][h * 4 + rr][cc];  // broadcast
                nacc[rr] = fmaf(v4.x, q0,
                           fmaf(v4.y, q1,
                           fmaf(v4.z, q2,
                           fmaf(v4.w, q3, nacc[rr]))));
            }
        }
        #pragma unroll
        for (int rr = 0; rr < 4; ++rr) acc[rr] = nacc[rr];
        p ^= 1;                                      // next step: other buffer
    }

    #pragma unroll
    for (int rr = 0; rr < 4; ++rr)
        P[((k << 7) | (r0 + h * 4 + rr)) * HALF + j] = acc[rr];
}

// ---------------------------------------------------------------------------
// K3: emit [B,S,256] = content ++ pos.  ROUND-2 VERIFIED FORM (NT stores).
// ---------------------------------------------------------------------------
__global__ __launch_bounds__(256) void emit_out(const int* __restrict__ tt,
                                                const int* __restrict__ tv,
                                                const int* __restrict__ np,
                                                const float* __restrict__ P,
                                                const float* __restrict__ emb,
                                                float* __restrict__ out) {
    const int i  = (blockIdx.x << 2) + (threadIdx.x >> 6);
    const int jj = (threadIdx.x & 63) << 2;
    const int ty = tt[i];
    const int v  = tv[i];
    f4 val;
    if (jj < 128) {
        if (ty == 0)      val = *(const f4*)&emb[jj];
        else if (ty == 1) val = *(const f4*)&emb[(v + 1) * HALF + jj];
        else if (ty == 2) val = *(const f4*)&emb[(v + 5) * HALF + jj];
        else if (ty == 4) {
            int vc = v < 0 ? 0 : (v > 4095 ? 4095 : v);
            val = *(const f4*)&P[vc * HALF + jj];
        } else if (v == -1) val = *(const f4*)&emb[10 * HALF + jj];
        else { f4 z = {0.f, 0.f, 0.f, 0.f}; val = z; }
    } else {
        const int p = np[i];
        val = *(const f4*)&P[p * HALF + (jj - 128)];
    }
    __builtin_nontemporal_store(val, (f4*)&out[i * 256 + jj]);
}

extern "C" void kernel_launch(void* const* d_in, const int* in_sizes, int n_in,
                              void* d_out, int out_size, void* d_ws, size_t ws_size,
                              hipStream_t stream) {
    const int*   token_types = (const int*)  d_in[0];
    const int*   token_vals  = (const int*)  d_in[1];
    const int*   node_pos    = (const int*)  d_in[2];
    const float* prim        = (const float*)d_in[3];
    const float* ident       = (const float*)d_in[4];
    const float* emb         = (const float*)d_in[5];
    float* out = (float*)d_out;

    // workspace: QT[2][128][128] at 0 | P[4096][128] at 262144.
    // K1's ping-pong W buffers live in the first 256 KB of the P region --
    // P is written only after K1 completes (stream-ordered), so no conflict.
    float* QT = (float*)d_ws;
    float* P  = (float*)((char*)d_ws + 262144);
    float* W0 = (float*)((char*)d_ws + 262144);
    float* W1 = (float*)((char*)d_ws + 262144 + 131072);

    k1_step<true,  false><<<16, 256, 0, stream>>>(prim, W0, W0, 0);  // N -> W0
    k1_step<false, false><<<16, 256, 0, stream>>>(prim, W0, W1, 1);
    k1_step<false, false><<<16, 256, 0, stream>>>(prim, W1, W0, 2);
    k1_step<false, false><<<16, 256, 0, stream>>>(prim, W0, W1, 3);
    k1_step<false, false><<<16, 256, 0, stream>>>(prim, W1, W0, 4);
    k1_step<false, false><<<16, 256, 0, stream>>>(prim, W0, W1, 5);
    k1_step<false, false><<<16, 256, 0, stream>>>(prim, W1, W0, 6);
    k1_step<false, true ><<<16, 256, 0, stream>>>(prim, W0, QT, 7);  // 2W - I

    path_base  <<<64,  256, 0, stream>>>(QT, ident, P);     // rows [0,256)
    path_upper <<<480, 256, 0, stream>>>(QT, P);            // rows [256,4096)
    emit_out   <<<NTOK / 4, 256, 0, stream>>>(token_types, token_vals, node_pos,
                                              P, emb, out);
}